// Round 7
// baseline (6172.519 us; speedup 1.0000x reference)
//
#include <hip/hip_runtime.h>

#define DEV static __device__ __forceinline__

DEV float sigf(float x) { return 1.0f / (1.0f + __expf(-x)); }
DEV float ftanh(float x) {
  float xc = fminf(fmaxf(x, -9.0f), 9.0f);
  float e = __expf(2.0f * xc);
  return (e - 1.0f) / (e + 1.0f);
}

// ---------------- generic tiled f32 GEMM (NT): out[m][n] = sum_k A[m][k]*B[n][k] + bias[n]
__global__ __launch_bounds__(256) void gemm_nt_bias(
    const float* __restrict__ A, const float* __restrict__ B,
    const float* __restrict__ bias, float* __restrict__ out,
    int M, int N, int K)
{
  __shared__ float As[64][17];
  __shared__ float Bs[64][17];
  const int tid = threadIdx.x;
  const int m0 = blockIdx.y * 64, n0 = blockIdx.x * 64;
  const int lr = tid >> 2;
  const int lk = (tid & 3) << 2;
  const int ty = tid >> 4, tx = tid & 15;
  float acc[4][4] = {};
  for (int k0 = 0; k0 < K; k0 += 16) {
    float4 a4 = *(const float4*)(A + (size_t)(m0 + lr) * K + k0 + lk);
    float4 b4 = *(const float4*)(B + (size_t)(n0 + lr) * K + k0 + lk);
    As[lr][lk] = a4.x; As[lr][lk + 1] = a4.y; As[lr][lk + 2] = a4.z; As[lr][lk + 3] = a4.w;
    Bs[lr][lk] = b4.x; Bs[lr][lk + 1] = b4.y; Bs[lr][lk + 2] = b4.z; Bs[lr][lk + 3] = b4.w;
    __syncthreads();
#pragma unroll
    for (int kk = 0; kk < 16; ++kk) {
      float av[4], bv[4];
#pragma unroll
      for (int r = 0; r < 4; ++r) av[r] = As[ty * 4 + r][kk];
#pragma unroll
      for (int c = 0; c < 4; ++c) bv[c] = Bs[tx * 4 + c][kk];
#pragma unroll
      for (int r = 0; r < 4; ++r)
#pragma unroll
        for (int c = 0; c < 4; ++c) acc[r][c] = fmaf(av[r], bv[c], acc[r][c]);
    }
    __syncthreads();
  }
#pragma unroll
  for (int r = 0; r < 4; ++r) {
    int m = m0 + ty * 4 + r;
#pragma unroll
    for (int c = 0; c < 4; ++c) {
      int n = n0 + tx * 4 + c;
      out[(size_t)m * N + n] = acc[r][c] + bias[n];
    }
  }
}

// ---------------- init: h_state = init_h; zero per-group barrier counters
__global__ void init_k(const float* __restrict__ init_h, float* __restrict__ h_state,
                       int* __restrict__ flags)
{
  int idx = blockIdx.x * 256 + threadIdx.x;
  if (idx < 16384) h_state[idx] = init_h[idx];
  if (blockIdx.x == 0 && threadIdx.x < 32) flags[threadIdx.x * 64] = 0;
}

struct P {
  const float* x;        // [32][32][2048]
  const float* pctx;     // [128][32][1024]
  const float* context;  // [128][32][1024]
  const float* init_c;   // [32][512]
  const float* x_mask;   // [128][32]
  const float* y_mask;   // [32][32]
  const float* U;        // [2048][512]
  const float* Wcomb;    // [1024][512]
  const float* U_att;    // [1024]
  const float* Ux;       // [2048][512]
  const float* Wx;       // [2048][1024]
  const float* bx;       // [2048]
  float* hs; float* cs; float* atts;
  float* h_state;        // [32][512]
  float* h1b;            // [32][512]
  float* c1b;            // [32][512]
  float* hpb;            // [32][1024]
  float* evb;            // [32][128]
  float* attb;           // [32][1024]
  int* flags;            // 32 counters, 64-int spacing
};

// intra-group (16-block) barrier: release fence -> count -> poll -> acquire fence
DEV void gbar(int* ctr, int target)
{
  __syncthreads();
  if (threadIdx.x == 0) {
    __threadfence();
    atomicAdd(ctr, 1);
    while (__hip_atomic_load(ctr, __ATOMIC_RELAXED, __HIP_MEMORY_SCOPE_AGENT) < target)
      __builtin_amdgcn_s_sleep(1);
    __threadfence();
  }
  __syncthreads();
}

// Persistent per-batch-group kernel: 512 blocks = 32 groups (one per b) x 16 blocks.
// All sync is intra-group; groups are fully independent.
__global__ __launch_bounds__(256, 2) void decode_k(P p)
{
  const int g = blockIdx.x >> 4;     // batch row b
  const int r = blockIdx.x & 15;     // rank within group
  const int tid = threadIdx.x;
  __shared__ float sm[2048];
  int* ctr = p.flags + g * 64;
  int phase = 0;

  for (int t = 0; t < 32; ++t) {
    const float* cprev = t ? p.cs + (size_t)(t - 1) * 16384 : p.init_c;
    const float* xt = p.x + (size_t)t * 65536;
    const float ymv = p.y_mask[t * 32 + g];

    // ---- P1: lstm1. Block owns j-slice [32r,32r+32) x 4 gates; 2 k-halves/row.
    {
      if (tid < 128) ((float4*)sm)[tid] = ((const float4*)(p.h_state + g * 512))[tid];
      __syncthreads();
      const int rl = tid & 127, kh = tid >> 7;
      const int gate = rl >> 5, jl = rl & 31;
      const int row = gate * 512 + r * 32 + jl;
      const float4* u4 = (const float4*)(p.U + (size_t)row * 512 + kh * 256);
      const float4* h4 = (const float4*)sm + kh * 64;
      float acc = 0.f;
#pragma unroll 8
      for (int k = 0; k < 64; ++k) {
        float4 uu = u4[k], hh = h4[k];
        acc = fmaf(uu.x, hh.x, fmaf(uu.y, hh.y, fmaf(uu.z, hh.z, fmaf(uu.w, hh.w, acc))));
      }
      sm[1024 + rl * 2 + kh] = acc;
      __syncthreads();
      if (tid < 32) {
        const int jj = r * 32 + tid;
        float pi = xt[g * 2048 + jj]         + sm[1024 + (tid) * 2]      + sm[1024 + (tid) * 2 + 1];
        float pf = xt[g * 2048 + 512 + jj]   + sm[1024 + (32 + tid) * 2] + sm[1024 + (32 + tid) * 2 + 1];
        float po = xt[g * 2048 + 1024 + jj]  + sm[1024 + (64 + tid) * 2] + sm[1024 + (64 + tid) * 2 + 1];
        float pg = xt[g * 2048 + 1536 + jj]  + sm[1024 + (96 + tid) * 2] + sm[1024 + (96 + tid) * 2 + 1];
        float cold = cprev[g * 512 + jj];
        float cn = sigf(pf) * cold + sigf(pi) * tanhf(pg);
        float hn = sigf(po) * tanhf(cn);
        float hm = ymv * hn + (1.f - ymv) * sm[jj];   // sm[0..511] = h_prev
        p.h1b[g * 512 + jj] = hm;
        p.c1b[g * 512 + jj] = cn;                     // unmasked, matches reference
      }
    }
    gbar(ctr, (++phase) * 16);

    // ---- P2: hproj c-slice [64r,64r+64); 4 k-quarters per c.
    {
      if (tid < 128) ((float4*)sm)[tid] = ((const float4*)(p.h1b + g * 512))[tid];
      __syncthreads();
      const int cl = tid >> 2, kq = tid & 3;
      const int c = r * 64 + cl;
      const float4* w4 = (const float4*)(p.Wcomb + (size_t)c * 512 + kq * 128);
      const float4* h4 = (const float4*)sm + kq * 32;
      float acc = 0.f;
#pragma unroll 8
      for (int k = 0; k < 32; ++k) {
        float4 ww = w4[k], hh = h4[k];
        acc = fmaf(ww.x, hh.x, fmaf(ww.y, hh.y, fmaf(ww.z, hh.z, fmaf(ww.w, hh.w, acc))));
      }
      sm[1024 + tid] = acc;
      __syncthreads();
      if (tid < 64) {
        float s = sm[1024 + tid * 4] + sm[1024 + tid * 4 + 1]
                + sm[1024 + tid * 4 + 2] + sm[1024 + tid * 4 + 3];
        p.hpb[g * 1024 + r * 64 + tid] = s;
      }
    }
    gbar(ctr, (++phase) * 16);

    // ---- P3: scores for t-slice [8r,8r+8); 32 lanes per t', 32 c each.
    {
      ((float4*)sm)[tid] = ((const float4*)(p.hpb + g * 1024))[tid & 255];      // hproj -> sm[0..1023]
      ((float4*)(sm + 1024))[tid] = ((const float4*)p.U_att)[tid & 255];        // U_att -> sm[1024..2047]
      __syncthreads();
      const int tloc = tid >> 5, tl = tid & 31;
      const int tt = r * 8 + tloc;
      const float4* pc = (const float4*)(p.pctx + ((size_t)tt * 32 + g) * 1024) + tl * 8;
      const float4* hp4 = (const float4*)sm + tl * 8;
      const float4* ua4 = (const float4*)(sm + 1024) + tl * 8;
      float acc = 0.f;
#pragma unroll
      for (int k = 0; k < 8; ++k) {
        float4 pv = pc[k], hv = hp4[k], uv = ua4[k];
        acc += ftanh(pv.x + hv.x) * uv.x + ftanh(pv.y + hv.y) * uv.y
             + ftanh(pv.z + hv.z) * uv.z + ftanh(pv.w + hv.w) * uv.w;
      }
#pragma unroll
      for (int off = 16; off > 0; off >>= 1) acc += __shfl_down(acc, off, 32);
      if (tl == 0) {
        float xm = p.x_mask[tt * 32 + g];
        p.evb[g * 128 + tt] = __expf(acc * xm) * xm;  // max-subtract cancels in ratio
      }
    }
    gbar(ctr, (++phase) * 16);

    // ---- P4: redundant softmax-sum + atted c-slice [64r,64r+64).
    {
      if (tid < 32) ((float4*)sm)[tid] = ((const float4*)(p.evb + g * 128))[tid];
      __syncthreads();
      if (tid < 64) {
        float s = sm[tid] + sm[tid + 64];
#pragma unroll
        for (int off = 32; off > 0; off >>= 1) s += __shfl_down(s, off);
        if (tid == 0) sm[192] = 1.0f / s;
      }
      __syncthreads();
      const float inv = sm[192];
      const int tl = tid & 63, tq = tid >> 6;
      const int c = r * 64 + tl;
      float acc = 0.f;
#pragma unroll 8
      for (int i = 0; i < 32; ++i) {
        int tt = tq * 32 + i;
        acc = fmaf(sm[tt], p.context[((size_t)tt * 32 + g) * 1024 + c], acc);
      }
      sm[256 + tq * 64 + tl] = acc;
      __syncthreads();
      if (tid < 64) {
        float tot = (sm[256 + tid] + sm[256 + 64 + tid]
                   + sm[256 + 128 + tid] + sm[256 + 192 + tid]) * inv;
        p.atts[(size_t)t * 32768 + g * 1024 + r * 64 + tid] = tot;
        p.attb[g * 1024 + r * 64 + tid] = tot;
      }
    }
    gbar(ctr, (++phase) * 16);

    // ---- P5: lstm2. Block owns j-slice [32r,32r+32) x 4 gates; 2 k-halves/row.
    {
      if (tid < 128) ((float4*)sm)[tid] = ((const float4*)(p.h1b + g * 512))[tid];
      ((float4*)(sm + 512))[tid] = ((const float4*)(p.attb + g * 1024))[tid & 255];
      __syncthreads();
      const int rl = tid & 127, kh = tid >> 7;
      const int gate = rl >> 5, jl = rl & 31;
      const int row = gate * 512 + r * 32 + jl;
      const float4* ux4 = (const float4*)(p.Ux + (size_t)row * 512 + kh * 256);
      const float4* wx4 = (const float4*)(p.Wx + (size_t)row * 1024 + kh * 512);
      const float4* h4 = (const float4*)sm + kh * 64;
      const float4* a4 = (const float4*)(sm + 512) + kh * 128;
      float acc = 0.f;
#pragma unroll 8
      for (int k = 0; k < 64; ++k) {
        float4 uu = ux4[k], hh = h4[k];
        acc = fmaf(uu.x, hh.x, fmaf(uu.y, hh.y, fmaf(uu.z, hh.z, fmaf(uu.w, hh.w, acc))));
      }
#pragma unroll 8
      for (int k = 0; k < 128; ++k) {
        float4 ww = wx4[k], aa = a4[k];
        acc = fmaf(ww.x, aa.x, fmaf(ww.y, aa.y, fmaf(ww.z, aa.z, fmaf(ww.w, aa.w, acc))));
      }
      sm[1536 + rl * 2 + kh] = acc;
      __syncthreads();
      if (tid < 32) {
        const int jj = r * 32 + tid;
        float pi = p.bx[jj]        + sm[1536 + (tid) * 2]      + sm[1536 + (tid) * 2 + 1];
        float pf = p.bx[512 + jj]  + sm[1536 + (32 + tid) * 2] + sm[1536 + (32 + tid) * 2 + 1];
        float po = p.bx[1024 + jj] + sm[1536 + (64 + tid) * 2] + sm[1536 + (64 + tid) * 2 + 1];
        float pg = p.bx[1536 + jj] + sm[1536 + (96 + tid) * 2] + sm[1536 + (96 + tid) * 2 + 1];
        float c1v = p.c1b[g * 512 + jj];
        float cn = sigf(pf) * c1v + sigf(pi) * tanhf(pg);
        float hn = sigf(po) * tanhf(cn);
        float hm = ymv * hn + (1.f - ymv) * sm[jj];   // sm[0..511] = h1
        p.hs[(size_t)t * 16384 + g * 512 + jj] = hm;
        p.cs[(size_t)t * 16384 + g * 512 + jj] = cn;
        p.h_state[g * 512 + jj] = hm;
      }
    }
    gbar(ctr, (++phase) * 16);
  }
}

extern "C" void kernel_launch(void* const* d_in, const int* in_sizes, int n_in,
                              void* d_out, int out_size, void* d_ws, size_t ws_size,
                              hipStream_t stream)
{
  const float* y_emb   = (const float*)d_in[0];
  const float* context = (const float*)d_in[1];
  const float* init_h  = (const float*)d_in[2];
  const float* init_c  = (const float*)d_in[3];
  const float* x_mask  = (const float*)d_in[4];
  const float* y_mask  = (const float*)d_in[5];
  const float* W       = (const float*)d_in[6];
  const float* U       = (const float*)d_in[7];
  const float* bvec    = (const float*)d_in[8];
  const float* Wx      = (const float*)d_in[9];
  const float* Ux      = (const float*)d_in[10];
  const float* bx      = (const float*)d_in[11];
  const float* Wc      = (const float*)d_in[12];
  const float* b_att   = (const float*)d_in[13];
  const float* Wcomb   = (const float*)d_in[14];
  const float* U_att   = (const float*)d_in[15];

  float* out  = (float*)d_out;
  float* hs   = out;
  float* cs   = out + (size_t)32 * 32 * 512;
  float* atts = out + (size_t)2 * 32 * 32 * 512;

  float* ws      = (float*)d_ws;
  float* pctx    = ws;                  // 4194304
  float* x       = pctx + 4194304;      // 2097152
  float* h_state = x + 2097152;         // 16384
  float* h1b     = h_state + 16384;     // 16384
  float* c1b     = h1b + 16384;         // 16384
  float* hpb     = c1b + 16384;         // 32768
  float* evb     = hpb + 32768;         // 4096
  float* attb    = evb + 4096;          // 32768
  int*   flags   = (int*)(attb + 32768);// 2048 ints

  gemm_nt_bias<<<dim3(16, 64), 256, 0, stream>>>(context, Wc, b_att, pctx, 4096, 1024, 1024);
  gemm_nt_bias<<<dim3(32, 16), 256, 0, stream>>>(y_emb, W, bvec, x, 1024, 2048, 256);
  init_k<<<64, 256, 0, stream>>>(init_h, h_state, flags);

  P p;
  p.x = x; p.pctx = pctx; p.context = context;
  p.init_c = init_c; p.x_mask = x_mask; p.y_mask = y_mask;
  p.U = U; p.Wcomb = Wcomb; p.U_att = U_att;
  p.Ux = Ux; p.Wx = Wx; p.bx = bx;
  p.hs = hs; p.cs = cs; p.atts = atts;
  p.h_state = h_state; p.h1b = h1b; p.c1b = c1b;
  p.hpb = hpb; p.evb = evb; p.attb = attb;
  p.flags = flags;

  decode_k<<<512, 256, 0, stream>>>(p);
}

// Round 8
// 3089.869 us; speedup vs baseline: 1.9977x; 1.9977x over previous
//
#include <hip/hip_runtime.h>

#define DEV static __device__ __forceinline__

DEV float sigf(float x) { return 1.0f / (1.0f + __expf(-x)); }
DEV float ftanh(float x) {
  float xc = fminf(fmaxf(x, -9.0f), 9.0f);
  float e = __expf(2.0f * xc);
  return (e - 1.0f) / (e + 1.0f);
}

// L3-coherent (agent-scope, relaxed, no fence) access helpers
DEV float ald(const float* p) { return __hip_atomic_load(p, __ATOMIC_RELAXED, __HIP_MEMORY_SCOPE_AGENT); }
DEV void  ast(float* p, float v) { __hip_atomic_store(p, v, __ATOMIC_RELAXED, __HIP_MEMORY_SCOPE_AGENT); }
DEV int   aldi(const int* p) { return __hip_atomic_load(p, __ATOMIC_RELAXED, __HIP_MEMORY_SCOPE_AGENT); }
DEV void  asti(int* p, int v) { __hip_atomic_store(p, v, __ATOMIC_RELAXED, __HIP_MEMORY_SCOPE_AGENT); }

// ---------------- generic tiled f32 GEMM (NT): out[m][n] = sum_k A[m][k]*B[n][k] + bias[n]
__global__ __launch_bounds__(256) void gemm_nt_bias(
    const float* __restrict__ A, const float* __restrict__ B,
    const float* __restrict__ bias, float* __restrict__ out,
    int M, int N, int K)
{
  __shared__ float As[64][17];
  __shared__ float Bs[64][17];
  const int tid = threadIdx.x;
  const int m0 = blockIdx.y * 64, n0 = blockIdx.x * 64;
  const int lr = tid >> 2;
  const int lk = (tid & 3) << 2;
  const int ty = tid >> 4, tx = tid & 15;
  float acc[4][4] = {};
  for (int k0 = 0; k0 < K; k0 += 16) {
    float4 a4 = *(const float4*)(A + (size_t)(m0 + lr) * K + k0 + lk);
    float4 b4 = *(const float4*)(B + (size_t)(n0 + lr) * K + k0 + lk);
    As[lr][lk] = a4.x; As[lr][lk + 1] = a4.y; As[lr][lk + 2] = a4.z; As[lr][lk + 3] = a4.w;
    Bs[lr][lk] = b4.x; Bs[lr][lk + 1] = b4.y; Bs[lr][lk + 2] = b4.z; Bs[lr][lk + 3] = b4.w;
    __syncthreads();
#pragma unroll
    for (int kk = 0; kk < 16; ++kk) {
      float av[4], bv[4];
#pragma unroll
      for (int r = 0; r < 4; ++r) av[r] = As[ty * 4 + r][kk];
#pragma unroll
      for (int c = 0; c < 4; ++c) bv[c] = Bs[tx * 4 + c][kk];
#pragma unroll
      for (int r = 0; r < 4; ++r)
#pragma unroll
        for (int c = 0; c < 4; ++c) acc[r][c] = fmaf(av[r], bv[c], acc[r][c]);
    }
    __syncthreads();
  }
#pragma unroll
  for (int r = 0; r < 4; ++r) {
    int m = m0 + ty * 4 + r;
#pragma unroll
    for (int c = 0; c < 4; ++c) {
      int n = n0 + tx * 4 + c;
      out[(size_t)m * N + n] = acc[r][c] + bias[n];
    }
  }
}

// zero the 160*512 phase flags (ws is re-poisoned 0xAA before every launch)
__global__ void init_k(int* __restrict__ flags)
{
  int i = blockIdx.x * 256 + threadIdx.x;
  if (i < 160 * 512) flags[i] = 0;
}

struct P {
  const float* x;        // [32][32][2048]
  const float* pctx;     // [128][32][1024]
  const float* context;  // [128][32][1024]
  const float* init_h;   // [32][512]
  const float* init_c;   // [32][512]
  const float* x_mask;   // [128][32]
  const float* y_mask;   // [32][32]
  const float* U;        // [2048][512]
  const float* Wcomb;    // [1024][512]
  const float* U_att;    // [1024]
  const float* Ux;       // [2048][512]
  const float* Wx;       // [2048][1024]
  const float* bx;       // [2048]
  float* hs; float* cs; float* atts;
  float* h1;             // [32][512]   (agent-atomic)
  float* c1;             // [32][512]   (agent-atomic)
  float* hp;             // [32][1024]  (agent-atomic)
  float* evb;            // [128][32]   (agent-atomic)
  float* attf;           // [32][1024]  (agent-atomic)
  float* h_state;        // [32][512]   (agent-atomic)
  int* flags;            // [160][512]
};

// fence-free phase barrier: per-block slot store + poll. __syncthreads drains
// vmcnt (data stores complete at L3) before the slot store is issued.
DEV void bar_phase(int* flags, int pg)
{
  __syncthreads();
  int* base = flags + pg * 512;
  if (threadIdx.x == 0) asti(base + blockIdx.x, 1);
  const int i0 = threadIdx.x * 2;
  while (aldi(base + i0) == 0 || aldi(base + i0 + 1) == 0)
    __builtin_amdgcn_s_sleep(2);
  __syncthreads();
}

// Persistent decoder: 512 blocks x 256 threads, 2 blocks/CU (LDS ~50KB) -> all resident.
__global__ __launch_bounds__(256, 2) void decode_k(P p)
{
  const int bid = blockIdx.x;
  const int tid = threadIdx.x;
  __shared__ float sm[12608];
  float* smH = sm;            // [8][516]  h slice
  float* smA = sm + 4128;     // [8][1028] att/hp slice
  float* sm2 = sm + 12352;    // [256] partials
  int pg = 0;

  for (int t = 0; t < 32; ++t) {
    // ================= P1: lstm1 (rows = 4 gates x 4 j, 8 b per block) =================
    {
      const float* hsrc = t ? p.h_state : p.init_h;
      const float* csrc = t ? p.cs + (size_t)(t - 1) * 16384 : p.init_c;
      const int bq = bid >> 7, jg = bid & 127, j0 = jg * 4, b0 = bq * 8;
      for (int i = tid; i < 4096; i += 256) {
        int br = i >> 9, k = i & 511;
        smH[br * 516 + k] = ald(hsrc + (size_t)(b0 + br) * 512 + k);
      }
      __syncthreads();
      const int half = tid >> 7, ri = (tid >> 3) & 15, bl = tid & 7;
      const int row = (ri >> 2) * 512 + j0 + (ri & 3);
      const float4* u4 = (const float4*)(p.U + (size_t)row * 512 + half * 256);
      const float4* h4 = (const float4*)(smH + bl * 516 + half * 256);
      float acc = 0.f;
#pragma unroll 8
      for (int k = 0; k < 64; ++k) {
        float4 a = u4[k], b = h4[k];
        acc = fmaf(a.x, b.x, fmaf(a.y, b.y, fmaf(a.z, b.z, fmaf(a.w, b.w, acc))));
      }
      sm2[half * 128 + ri * 8 + bl] = acc;
      __syncthreads();
      if (tid < 32) {
        const int jl = tid >> 3, bl2 = tid & 7;
        const int j = j0 + jl, b = b0 + bl2;
        const float* xrow = p.x + (size_t)t * 65536 + b * 2048;
        float pre[4];
#pragma unroll
        for (int g = 0; g < 4; ++g)
          pre[g] = xrow[g * 512 + j] + sm2[(g * 4 + jl) * 8 + bl2] + sm2[128 + (g * 4 + jl) * 8 + bl2];
        float cold = ald(csrc + b * 512 + j);
        float cn = sigf(pre[1]) * cold + sigf(pre[0]) * tanhf(pre[3]);
        float hn = sigf(pre[2]) * tanhf(cn);
        float ym = p.y_mask[t * 32 + b];
        float hm = ym * hn + (1.f - ym) * smH[bl2 * 516 + j];
        ast(p.h1 + b * 512 + j, hm);
        ast(p.c1 + b * 512 + j, cn);   // unmasked, matches reference
      }
    }
    bar_phase(p.flags, pg++);

    // ================= P2: hproj (8 d x 8 b per block, split-K x4) =================
    {
      const int bq = bid >> 7, dg = bid & 127, d0 = dg * 8, b0 = bq * 8;
      for (int i = tid; i < 4096; i += 256) {
        int br = i >> 9, k = i & 511;
        smH[br * 516 + k] = ald(p.h1 + (size_t)(b0 + br) * 512 + k);
      }
      __syncthreads();
      const int q = tid >> 6, dl = (tid >> 3) & 7, bl = tid & 7;
      const float4* w4 = (const float4*)(p.Wcomb + (size_t)(d0 + dl) * 512 + q * 128);
      const float4* h4 = (const float4*)(smH + bl * 516 + q * 128);
      float acc = 0.f;
#pragma unroll 8
      for (int k = 0; k < 32; ++k) {
        float4 a = w4[k], b = h4[k];
        acc = fmaf(a.x, b.x, fmaf(a.y, b.y, fmaf(a.z, b.z, fmaf(a.w, b.w, acc))));
      }
      sm2[tid] = acc;   // tid = q*64 + dl*8 + bl
      __syncthreads();
      if (tid < 64) {
        const int dl2 = tid >> 3, bl2 = tid & 7;
        float s = sm2[dl2 * 8 + bl2] + sm2[64 + dl2 * 8 + bl2]
                + sm2[128 + dl2 * 8 + bl2] + sm2[192 + dl2 * 8 + bl2];
        ast(p.hp + (size_t)(b0 + bl2) * 1024 + d0 + dl2, s);
      }
    }
    bar_phase(p.flags, pg++);

    // ================= P3: scores (1 t, 8 b per block; 32 lanes per (t,b)) =================
    {
      const int tsrc = bid >> 2, B0 = (bid & 3) * 8;
      for (int i = tid; i < 8192; i += 256) {
        int br = i >> 10, c = i & 1023;
        smA[br * 1028 + c] = ald(p.hp + (size_t)(B0 + br) * 1024 + c);
      }
      __syncthreads();
      const int s = tid >> 5, lane = tid & 31;
      const int b = B0 + s;
      const float4* pc = (const float4*)(p.pctx + ((size_t)tsrc * 32 + b) * 1024) + lane * 8;
      const float4* hv4 = (const float4*)(smA + s * 1028) + lane * 8;
      const float4* ua4 = (const float4*)p.U_att + lane * 8;
      float acc = 0.f;
#pragma unroll
      for (int k = 0; k < 8; ++k) {
        float4 pv = pc[k], hv = hv4[k], uv = ua4[k];
        acc += ftanh(pv.x + hv.x) * uv.x + ftanh(pv.y + hv.y) * uv.y
             + ftanh(pv.z + hv.z) * uv.z + ftanh(pv.w + hv.w) * uv.w;
      }
#pragma unroll
      for (int off = 16; off > 0; off >>= 1) acc += __shfl_down(acc, off, 32);
      if (lane == 0) {
        float xm = p.x_mask[tsrc * 32 + b];
        ast(p.evb + tsrc * 32 + b, __expf(acc * xm) * xm);  // max-subtract cancels in ratio
      }
    }
    bar_phase(p.flags, pg++);

    // ================= P4: softmax-normalize + atted (1 b, 64 c per block) =================
    {
      const int b = bid >> 4, cch = bid & 15;
      if (tid < 128) sm[tid] = ald(p.evb + tid * 32 + b);
      __syncthreads();
      if (tid < 64) {
        float s = sm[tid] + sm[tid + 64];
#pragma unroll
        for (int off = 32; off > 0; off >>= 1) s += __shfl_down(s, off);
        if (tid == 0) sm[130] = 1.0f / s;
      }
      __syncthreads();
      const float inv = sm[130];
      const int tq = tid >> 6, cl = tid & 63;
      const int c = cch * 64 + cl;
      float acc = 0.f;
#pragma unroll 8
      for (int i = 0; i < 32; ++i) {
        int tt = tq * 32 + i;
        acc = fmaf(sm[tt], p.context[((size_t)tt * 32 + b) * 1024 + c], acc);
      }
      __syncthreads();
      sm2[tid] = acc;   // tid = tq*64 + cl
      __syncthreads();
      if (tid < 64) {
        float tot = (sm2[tid] + sm2[64 + tid] + sm2[128 + tid] + sm2[192 + tid]) * inv;
        const int c2 = cch * 64 + tid;
        p.atts[(size_t)t * 32768 + b * 1024 + c2] = tot;  // pure output: normal store
        ast(p.attf + b * 1024 + c2, tot);
      }
    }
    bar_phase(p.flags, pg++);

    // ================= P5: lstm2 (rows = 4 gates x 4 j, 8 b per block) =================
    {
      const int bq = bid >> 7, jg = bid & 127, j0 = jg * 4, b0 = bq * 8;
      for (int i = tid; i < 4096; i += 256) {
        int br = i >> 9, k = i & 511;
        smH[br * 516 + k] = ald(p.h1 + (size_t)(b0 + br) * 512 + k);
      }
      for (int i = tid; i < 8192; i += 256) {
        int br = i >> 10, c = i & 1023;
        smA[br * 1028 + c] = ald(p.attf + (size_t)(b0 + br) * 1024 + c);
      }
      __syncthreads();
      const int half = tid >> 7, ri = (tid >> 3) & 15, bl = tid & 7;
      const int row = (ri >> 2) * 512 + j0 + (ri & 3);
      const float4* ux4 = (const float4*)(p.Ux + (size_t)row * 512 + half * 256);
      const float4* wx4 = (const float4*)(p.Wx + (size_t)row * 1024 + half * 512);
      const float4* h4 = (const float4*)(smH + bl * 516 + half * 256);
      const float4* a4 = (const float4*)(smA + bl * 1028 + half * 512);
      float acc = 0.f;
#pragma unroll 8
      for (int k = 0; k < 64; ++k) {
        float4 a = ux4[k], b = h4[k];
        acc = fmaf(a.x, b.x, fmaf(a.y, b.y, fmaf(a.z, b.z, fmaf(a.w, b.w, acc))));
      }
#pragma unroll 8
      for (int k = 0; k < 128; ++k) {
        float a2 = 0.f;
        float4 w = wx4[k], a = a4[k];
        a2 = fmaf(w.x, a.x, fmaf(w.y, a.y, fmaf(w.z, a.z, fmaf(w.w, a.w, 0.f))));
        acc += a2;
      }
      sm2[half * 128 + ri * 8 + bl] = acc;
      __syncthreads();
      if (tid < 32) {
        const int jl = tid >> 3, bl2 = tid & 7;
        const int j = j0 + jl, b = b0 + bl2;
        float pre[4];
#pragma unroll
        for (int g = 0; g < 4; ++g)
          pre[g] = p.bx[g * 512 + j] + sm2[(g * 4 + jl) * 8 + bl2] + sm2[128 + (g * 4 + jl) * 8 + bl2];
        float c1v = ald(p.c1 + b * 512 + j);
        float cn = sigf(pre[1]) * c1v + sigf(pre[0]) * tanhf(pre[3]);
        float hn = sigf(pre[2]) * tanhf(cn);
        float ym = p.y_mask[t * 32 + b];
        float hm = ym * hn + (1.f - ym) * smH[bl2 * 516 + j];
        p.hs[(size_t)t * 16384 + b * 512 + j] = hm;       // pure output: normal store
        ast(p.cs + (size_t)t * 16384 + b * 512 + j, cn);  // re-read as cprev next step
        ast(p.h_state + b * 512 + j, hm);
      }
    }
    bar_phase(p.flags, pg++);
  }
}

extern "C" void kernel_launch(void* const* d_in, const int* in_sizes, int n_in,
                              void* d_out, int out_size, void* d_ws, size_t ws_size,
                              hipStream_t stream)
{
  const float* y_emb   = (const float*)d_in[0];
  const float* context = (const float*)d_in[1];
  const float* init_h  = (const float*)d_in[2];
  const float* init_c  = (const float*)d_in[3];
  const float* x_mask  = (const float*)d_in[4];
  const float* y_mask  = (const float*)d_in[5];
  const float* W       = (const float*)d_in[6];
  const float* U       = (const float*)d_in[7];
  const float* bvec    = (const float*)d_in[8];
  const float* Wx      = (const float*)d_in[9];
  const float* Ux      = (const float*)d_in[10];
  const float* bx      = (const float*)d_in[11];
  const float* Wc      = (const float*)d_in[12];
  const float* b_att   = (const float*)d_in[13];
  const float* Wcomb   = (const float*)d_in[14];
  const float* U_att   = (const float*)d_in[15];

  float* out  = (float*)d_out;
  float* hs   = out;
  float* cs   = out + (size_t)32 * 32 * 512;
  float* atts = out + (size_t)2 * 32 * 32 * 512;

  float* ws      = (float*)d_ws;
  float* pctx    = ws;                   // 4194304
  float* x       = pctx + 4194304;       // 2097152
  float* h1      = x + 2097152;          // 16384
  float* c1      = h1 + 16384;           // 16384
  float* hp      = c1 + 16384;           // 32768
  float* evb     = hp + 32768;           // 4096
  float* attf    = evb + 4096;           // 32768
  float* h_state = attf + 32768;         // 16384
  int*   flags   = (int*)(h_state + 16384);  // 160*512 ints

  gemm_nt_bias<<<dim3(16, 64), 256, 0, stream>>>(context, Wc, b_att, pctx, 4096, 1024, 1024);
  gemm_nt_bias<<<dim3(32, 16), 256, 0, stream>>>(y_emb, W, bvec, x, 1024, 2048, 256);
  init_k<<<320, 256, 0, stream>>>(flags);

  P p;
  p.x = x; p.pctx = pctx; p.context = context;
  p.init_h = init_h; p.init_c = init_c;
  p.x_mask = x_mask; p.y_mask = y_mask;
  p.U = U; p.Wcomb = Wcomb; p.U_att = U_att;
  p.Ux = Ux; p.Wx = Wx; p.bx = bx;
  p.hs = hs; p.cs = cs; p.atts = atts;
  p.h1 = h1; p.c1 = c1; p.hp = hp;
  p.evb = evb; p.attf = attf; p.h_state = h_state;
  p.flags = flags;

  decode_k<<<512, 256, 0, stream>>>(p);
}

// Round 9
// 2127.336 us; speedup vs baseline: 2.9015x; 1.4525x over previous
//
#include <hip/hip_runtime.h>

#define DEV static __device__ __forceinline__

typedef __attribute__((ext_vector_type(4))) float f32x4;

DEV float sigf(float x) { return 1.0f / (1.0f + __expf(-x)); }
DEV float ftanh(float x) {
  float xc = fminf(fmaxf(x, -9.0f), 9.0f);
  float e = __expf(2.0f * xc);
  return (e - 1.0f) / (e + 1.0f);
}

// flags: agent-scope (L3) atomics — mapping-independent, hang-proof
DEV int  aldi(const int* p) { return __hip_atomic_load(p, __ATOMIC_RELAXED, __HIP_MEMORY_SCOPE_AGENT); }
DEV void asti(int* p, int v) { __hip_atomic_store(p, v, __ATOMIC_RELAXED, __HIP_MEMORY_SCOPE_AGENT); }

// data: L1-bypass (sc0) loads — coherent through the XCD's L2
DEV f32x4 ld4_sc0(const float* p) {
  f32x4 v;
  asm volatile("global_load_dwordx4 %0, %1, off sc0\n\ts_waitcnt vmcnt(0)"
               : "=v"(v) : "v"(p) : "memory");
  return v;
}
DEV float ld_sc0(const float* p) {
  float v;
  asm volatile("global_load_dword %0, %1, off sc0\n\ts_waitcnt vmcnt(0)"
               : "=v"(v) : "v"(p) : "memory");
  return v;
}

// ---------------- generic tiled f32 GEMM (NT): out = A @ B^T + bias
__global__ __launch_bounds__(256) void gemm_nt_bias(
    const float* __restrict__ A, const float* __restrict__ B,
    const float* __restrict__ bias, float* __restrict__ out,
    int M, int N, int K)
{
  __shared__ float As[64][17];
  __shared__ float Bs[64][17];
  const int tid = threadIdx.x;
  const int m0 = blockIdx.y * 64, n0 = blockIdx.x * 64;
  const int lr = tid >> 2;
  const int lk = (tid & 3) << 2;
  const int ty = tid >> 4, tx = tid & 15;
  float acc[4][4] = {};
  for (int k0 = 0; k0 < K; k0 += 16) {
    float4 a4 = *(const float4*)(A + (size_t)(m0 + lr) * K + k0 + lk);
    float4 b4 = *(const float4*)(B + (size_t)(n0 + lr) * K + k0 + lk);
    As[lr][lk] = a4.x; As[lr][lk + 1] = a4.y; As[lr][lk + 2] = a4.z; As[lr][lk + 3] = a4.w;
    Bs[lr][lk] = b4.x; Bs[lr][lk + 1] = b4.y; Bs[lr][lk + 2] = b4.z; Bs[lr][lk + 3] = b4.w;
    __syncthreads();
#pragma unroll
    for (int kk = 0; kk < 16; ++kk) {
      float av[4], bv[4];
#pragma unroll
      for (int r = 0; r < 4; ++r) av[r] = As[ty * 4 + r][kk];
#pragma unroll
      for (int c = 0; c < 4; ++c) bv[c] = Bs[tx * 4 + c][kk];
#pragma unroll
      for (int r = 0; r < 4; ++r)
#pragma unroll
        for (int c = 0; c < 4; ++c) acc[r][c] = fmaf(av[r], bv[c], acc[r][c]);
    }
    __syncthreads();
  }
#pragma unroll
  for (int r = 0; r < 4; ++r) {
    int m = m0 + ty * 4 + r;
#pragma unroll
    for (int c = 0; c < 4; ++c) {
      int n = n0 + tx * 4 + c;
      out[(size_t)m * N + n] = acc[r][c] + bias[n];
    }
  }
}

__global__ void init_k(int* __restrict__ flags)
{
  int i = blockIdx.x * 256 + threadIdx.x;
  if (i < 160 * 512) flags[i] = 0;
}

struct P {
  const float* x;        // [32*32][2048]  rows t*32+b
  const float* pctx;     // [128*32][1024] rows t*32+b
  const float* context;  // [128*32][1024]
  const float* init_h;   // [32][512]
  const float* init_c;   // [32][512]
  const float* x_mask;   // [128][32]
  const float* y_mask;   // [32][32]
  const float* U;        // [2048][512]
  const float* Wcomb;    // [1024][512]
  const float* U_att;    // [1024]
  const float* Ux;       // [2048][512]
  const float* Wx;       // [2048][1024]
  const float* bx;       // [2048]
  float* hs; float* cs; float* atts;
  float* h1;             // [32][512]
  float* hp;             // [32][1024]
  float* evb;            // [128][32]
  float* attf;           // [32][1024]
  float* h_state;        // [32][512]
  int* flags;            // [160][512]
};

// group barrier: 64 slot-flags per (phase, group); store own, poll all.
DEV void gbar(int* flags, int pg, int g, int r)
{
  __syncthreads();                 // drains vmcnt -> block's stores are in L2
  int* base = flags + pg * 512 + g * 64;
  if (threadIdx.x == 0) asti(base + r, 1);
  if (threadIdx.x < 64) {
    while (aldi(base + threadIdx.x) == 0) __builtin_amdgcn_s_sleep(2);
  }
  __syncthreads();
}

// Persistent decoder: 512 blocks x 256 threads (2/CU, all resident).
// Group g = {bid % 8 == g} (one XCD), owns batch rows [4g, 4g+4).
__global__ __launch_bounds__(256, 2) void decode_k(P p)
{
  const int bid = blockIdx.x, tid = threadIdx.x;
  const int g = bid & 7;          // presumed XCD
  const int r = bid >> 3;         // rank 0..63 within group
  const int b0 = g * 4;           // first batch row of this group
  const int j0 = r * 8;           // this block's j-slice (P1/P5)

  __shared__ float smS[6160];     // staging: max 4*1540 floats (P5)
  __shared__ float sm2[256];
  __shared__ float smE[128];
  __shared__ float sInv;
  __shared__ float smC[4][8];     // c-state for this block's (b, j)-slice

  if (tid < 32) smC[tid & 3][tid >> 2] = p.init_c[(b0 + (tid & 3)) * 512 + j0 + (tid >> 2)];
  __syncthreads();

  int pg = 0;
  for (int t = 0; t < 32; ++t) {
    // ======== P1: lstm1 — block computes rows {4 gates x 8 j} for 4 b ========
    {
      const float* hsrc = t ? p.h_state : p.init_h;
      for (int i = tid; i < 512; i += 256) {       // 512 float4 = 4b x 512
        int bl = i >> 7, k4 = i & 127;
        ((f32x4*)smS)[bl * 129 + k4] = ld4_sc0(hsrc + (size_t)(b0 + bl) * 512 + k4 * 4);
      }
      __syncthreads();
      const int bl = tid & 3, row = (tid >> 2) & 31, kh = tid >> 7;
      const int gate = row >> 3, jl = row & 7;
      const f32x4* u4 = (const f32x4*)(p.U + (size_t)(gate * 512 + j0 + jl) * 512 + kh * 256);
      const f32x4* h4 = (const f32x4*)(smS + bl * 516 + kh * 256);
      float acc = 0.f;
#pragma unroll 8
      for (int k = 0; k < 64; ++k) {
        f32x4 a = u4[k], h = h4[k];
        acc = fmaf(a.x, h.x, fmaf(a.y, h.y, fmaf(a.z, h.z, fmaf(a.w, h.w, acc))));
      }
      sm2[kh * 128 + row * 4 + bl] = acc;
      __syncthreads();
      if (tid < 32) {
        const int bl2 = tid & 3, jl2 = tid >> 2;
        const int b = b0 + bl2, j = j0 + jl2;
        const float* xrow = p.x + (size_t)(t * 32 + b) * 2048;
        float pre[4];
#pragma unroll
        for (int g4 = 0; g4 < 4; ++g4)
          pre[g4] = xrow[g4 * 512 + j] + sm2[(g4 * 8 + jl2) * 4 + bl2] + sm2[128 + (g4 * 8 + jl2) * 4 + bl2];
        float cold = smC[bl2][jl2];
        float cn = sigf(pre[1]) * cold + sigf(pre[0]) * tanhf(pre[3]);
        float hn = sigf(pre[2]) * tanhf(cn);
        float ym = p.y_mask[t * 32 + b];
        float hm = ym * hn + (1.f - ym) * smS[bl2 * 516 + j];
        p.h1[b * 512 + j] = hm;
        smC[bl2][jl2] = cn;        // c1 (unmasked) — consumed by P5 in this same block
      }
    }
    gbar(p.flags, pg++, g, r);

    // ======== P2: hproj — block computes d-slice [16r,16r+16) for 4 b ========
    {
      for (int i = tid; i < 512; i += 256) {
        int bl = i >> 7, k4 = i & 127;
        ((f32x4*)smS)[bl * 129 + k4] = ld4_sc0(p.h1 + (size_t)(b0 + bl) * 512 + k4 * 4);
      }
      __syncthreads();
      const int bl = tid & 3, dl = (tid >> 2) & 15, kq = tid >> 6;
      const f32x4* w4 = (const f32x4*)(p.Wcomb + (size_t)(r * 16 + dl) * 512 + kq * 128);
      const f32x4* h4 = (const f32x4*)(smS + bl * 516 + kq * 128);
      float acc = 0.f;
#pragma unroll 8
      for (int k = 0; k < 32; ++k) {
        f32x4 a = w4[k], h = h4[k];
        acc = fmaf(a.x, h.x, fmaf(a.y, h.y, fmaf(a.z, h.z, fmaf(a.w, h.w, acc))));
      }
      sm2[kq * 64 + dl * 4 + bl] = acc;
      __syncthreads();
      if (tid < 64) {
        const int dl2 = tid >> 2, bl2 = tid & 3;
        float s = sm2[dl2 * 4 + bl2] + sm2[64 + dl2 * 4 + bl2]
                + sm2[128 + dl2 * 4 + bl2] + sm2[192 + dl2 * 4 + bl2];
        p.hp[(size_t)(b0 + bl2) * 1024 + r * 16 + dl2] = s;
      }
    }
    gbar(p.flags, pg++, g, r);

    // ======== P3: scores — block computes t-pair {2r, 2r+1} x 4 b ========
    {
      for (int i = tid; i < 1024; i += 256) {      // 4b x 256 float4
        int bl = i >> 8, c4 = i & 255;
        ((f32x4*)smS)[bl * 257 + c4] = ld4_sc0(p.hp + (size_t)(b0 + bl) * 1024 + c4 * 4);
      }
      __syncthreads();
      const int lane = tid & 31, bl = (tid >> 5) & 3, tl = tid >> 7;
      const int tt = r * 2 + tl, b = b0 + bl;
      const f32x4* pc = (const f32x4*)(p.pctx + ((size_t)tt * 32 + b) * 1024);
      const f32x4* hv = (const f32x4*)smS + bl * 257;
      const f32x4* ua = (const f32x4*)p.U_att;
      float acc = 0.f;
#pragma unroll
      for (int k = 0; k < 8; ++k) {
        int idx = lane + 32 * k;
        f32x4 pv = pc[idx], hh = hv[idx], uv = ua[idx];
        acc += ftanh(pv.x + hh.x) * uv.x + ftanh(pv.y + hh.y) * uv.y
             + ftanh(pv.z + hh.z) * uv.z + ftanh(pv.w + hh.w) * uv.w;
      }
#pragma unroll
      for (int off = 16; off > 0; off >>= 1) acc += __shfl_down(acc, off, 32);
      if (lane == 0) {
        float xm = p.x_mask[tt * 32 + b];
        p.evb[tt * 32 + b] = __expf(acc * xm) * xm;   // max-subtract cancels in ratio
      }
    }
    gbar(p.flags, pg++, g, r);

    // ======== P4: softmax-normalize + atted — block = (b, 64-c chunk) ========
    {
      const int bl = r >> 4, cch = r & 15;
      const int b = b0 + bl, c0 = cch * 64;
      if (tid < 128) smE[tid] = ld_sc0(p.evb + tid * 32 + b);
      __syncthreads();
      if (tid < 64) {
        float s = smE[tid] + smE[tid + 64];
#pragma unroll
        for (int off = 32; off > 0; off >>= 1) s += __shfl_down(s, off);
        if (tid == 0) sInv = 1.0f / s;
      }
      __syncthreads();
      const float inv = sInv;
      const int tq = tid >> 6, cl = tid & 63;
      float acc = 0.f;
#pragma unroll 8
      for (int i = 0; i < 32; ++i) {
        int tt = tq * 32 + i;
        acc = fmaf(smE[tt], p.context[((size_t)tt * 32 + b) * 1024 + c0 + cl], acc);
      }
      sm2[tq * 64 + cl] = acc;
      __syncthreads();
      if (tid < 64) {
        float tot = (sm2[tid] + sm2[64 + tid] + sm2[128 + tid] + sm2[192 + tid]) * inv;
        p.atts[(size_t)t * 32768 + b * 1024 + c0 + tid] = tot;
        p.attf[(size_t)b * 1024 + c0 + tid] = tot;
      }
    }
    gbar(p.flags, pg++, g, r);

    // ======== P5: lstm2 — block computes rows {4 gates x 8 j} for 4 b ========
    {
      for (int i = tid; i < 512; i += 256) {       // h1: 4b x 128 float4
        int bl = i >> 7, k4 = i & 127;
        ((f32x4*)smS)[bl * 385 + k4] = ld4_sc0(p.h1 + (size_t)(b0 + bl) * 512 + k4 * 4);
      }
      for (int i = tid; i < 1024; i += 256) {      // attf: 4b x 256 float4
        int bl = i >> 8, c4 = i & 255;
        ((f32x4*)smS)[bl * 385 + 129 + c4] = ld4_sc0(p.attf + (size_t)(b0 + bl) * 1024 + c4 * 4);
      }
      __syncthreads();
      const int bl = tid & 3, row = (tid >> 2) & 31, kh = tid >> 7;
      const int gate = row >> 3, jl = row & 7;
      const int rowi = gate * 512 + j0 + jl;
      const f32x4* ux4 = (const f32x4*)(p.Ux + (size_t)rowi * 512 + kh * 256);
      const f32x4* wx4 = (const f32x4*)(p.Wx + (size_t)rowi * 1024 + kh * 512);
      const f32x4* h4 = (const f32x4*)(smS + bl * 1540 + kh * 256);
      const f32x4* a4 = (const f32x4*)(smS + bl * 1540 + 516 + kh * 512);
      float acc = 0.f;
#pragma unroll 8
      for (int k = 0; k < 64; ++k) {
        f32x4 a = ux4[k], h = h4[k];
        acc = fmaf(a.x, h.x, fmaf(a.y, h.y, fmaf(a.z, h.z, fmaf(a.w, h.w, acc))));
      }
#pragma unroll 8
      for (int k = 0; k < 128; ++k) {
        f32x4 w = wx4[k], a = a4[k];
        acc = fmaf(w.x, a.x, fmaf(w.y, a.y, fmaf(w.z, a.z, fmaf(w.w, a.w, acc))));
      }
      sm2[kh * 128 + row * 4 + bl] = acc;
      __syncthreads();
      if (tid < 32) {
        const int bl2 = tid & 3, jl2 = tid >> 2;
        const int b = b0 + bl2, j = j0 + jl2;
        float pre[4];
#pragma unroll
        for (int g4 = 0; g4 < 4; ++g4)
          pre[g4] = p.bx[g4 * 512 + j] + sm2[(g4 * 8 + jl2) * 4 + bl2] + sm2[128 + (g4 * 8 + jl2) * 4 + bl2];
        float c1v = smC[bl2][jl2];
        float cn = sigf(pre[1]) * c1v + sigf(pre[0]) * tanhf(pre[3]);
        float hn = sigf(pre[2]) * tanhf(cn);
        float ym = p.y_mask[t * 32 + b];
        float hf = smS[bl2 * 1540 + j];            // h1 fallback
        float hm = ym * hn + (1.f - ym) * hf;
        p.hs[(size_t)t * 16384 + b * 512 + j] = hm;
        p.cs[(size_t)t * 16384 + b * 512 + j] = cn;
        p.h_state[b * 512 + j] = hm;
        smC[bl2][jl2] = cn;                        // c-state for next step
      }
    }
    gbar(p.flags, pg++, g, r);
  }
}

extern "C" void kernel_launch(void* const* d_in, const int* in_sizes, int n_in,
                              void* d_out, int out_size, void* d_ws, size_t ws_size,
                              hipStream_t stream)
{
  const float* y_emb   = (const float*)d_in[0];
  const float* context = (const float*)d_in[1];
  const float* init_h  = (const float*)d_in[2];
  const float* init_c  = (const float*)d_in[3];
  const float* x_mask  = (const float*)d_in[4];
  const float* y_mask  = (const float*)d_in[5];
  const float* W       = (const float*)d_in[6];
  const float* U       = (const float*)d_in[7];
  const float* bvec    = (const float*)d_in[8];
  const float* Wx      = (const float*)d_in[9];
  const float* Ux      = (const float*)d_in[10];
  const float* bx      = (const float*)d_in[11];
  const float* Wc      = (const float*)d_in[12];
  const float* b_att   = (const float*)d_in[13];
  const float* Wcomb   = (const float*)d_in[14];
  const float* U_att   = (const float*)d_in[15];

  float* out  = (float*)d_out;
  float* hs   = out;
  float* cs   = out + (size_t)32 * 32 * 512;
  float* atts = out + (size_t)2 * 32 * 32 * 512;

  float* ws      = (float*)d_ws;
  float* pctx    = ws;                   // 4194304
  float* x       = pctx + 4194304;       // 2097152
  float* h1      = x + 2097152;          // 16384
  float* hp      = h1 + 16384;           // 32768
  float* evb     = hp + 32768;           // 4096
  float* attf    = evb + 4096;           // 32768
  float* h_state = attf + 32768;         // 16384
  int*   flags   = (int*)(h_state + 16384);  // 160*512 ints

  gemm_nt_bias<<<dim3(16, 64), 256, 0, stream>>>(context, Wc, b_att, pctx, 4096, 1024, 1024);
  gemm_nt_bias<<<dim3(32, 16), 256, 0, stream>>>(y_emb, W, bvec, x, 1024, 2048, 256);
  init_k<<<320, 256, 0, stream>>>(flags);

  P p;
  p.x = x; p.pctx = pctx; p.context = context;
  p.init_h = init_h; p.init_c = init_c;
  p.x_mask = x_mask; p.y_mask = y_mask;
  p.U = U; p.Wcomb = Wcomb; p.U_att = U_att;
  p.Ux = Ux; p.Wx = Wx; p.bx = bx;
  p.hs = hs; p.cs = cs; p.atts = atts;
  p.h1 = h1; p.hp = hp; p.evb = evb;
  p.attf = attf; p.h_state = h_state;
  p.flags = flags;

  decode_k<<<512, 256, 0, stream>>>(p);
}